// Round 10
// baseline (351.922 us; speedup 1.0000x reference)
//
#include <hip/hip_runtime.h>
#include <cstdint>

typedef short bf16x8 __attribute__((ext_vector_type(8)));
typedef float f32x4  __attribute__((ext_vector_type(4)));

#define TOK    64         // tokens per block
#define CH     64         // codes per chunk
#define NCH    16         // chunks (K=1024)
#define BUFW   16384      // ushorts per chunk buffer (64 rows x 256)
#define MAXC   32

static __device__ __forceinline__ unsigned umn(unsigned a, unsigned b) { return a < b ? a : b; }
static __device__ __forceinline__ unsigned umx(unsigned a, unsigned b) { return a > b ? a : b; }

__device__ __forceinline__ unsigned short f2bf(float f) {
  unsigned u = __float_as_uint(f);
  return (unsigned short)((u + 0x7FFFu + ((u >> 16) & 1u)) >> 16);
}
__device__ __forceinline__ uint4 pack8(float4 a, float4 b) {
  uint4 u;
  u.x = (unsigned)f2bf(a.x) | ((unsigned)f2bf(a.y) << 16);
  u.y = (unsigned)f2bf(a.z) | ((unsigned)f2bf(a.w) << 16);
  u.z = (unsigned)f2bf(b.x) | ((unsigned)f2bf(b.y) << 16);
  u.w = (unsigned)f2bf(b.z) | ((unsigned)f2bf(b.w) << 16);
  return u;
}
// async global->LDS DMA, 16 B per lane. LDS dest = wave-uniform base + lane*16.
__device__ __forceinline__ void gload16(const unsigned short* g, unsigned short* l) {
  __builtin_amdgcn_global_load_lds(
      (const __attribute__((address_space(1))) unsigned int*)(const void*)g,
      (__attribute__((address_space(3))) unsigned int*)(void*)l, 16, 0, 0);
}

// ---------------------------------------------------------------------------
// Prep: cb_bf = bf16(cb), ee = ||cb_k||^2. Block 0 zeroes global accumulators.
// ---------------------------------------------------------------------------
__global__ __launch_bounds__(256) void vq_prep(const float* __restrict__ cb,
                                               unsigned short* __restrict__ cb_bf,
                                               float* __restrict__ ee,
                                               float* __restrict__ acc2,
                                               int* __restrict__ done_ctr, int K) {
  if (blockIdx.x == 0 && threadIdx.x == 0) {
    acc2[0] = 0.f; acc2[1] = 0.f; *done_ctr = 0;
  }
  int wave = threadIdx.x >> 6, lane = threadIdx.x & 63;
  int k = blockIdx.x * 4 + wave;
  if (k >= K) return;
  float4 v = *reinterpret_cast<const float4*>(cb + (size_t)k * 256 + lane * 4);
  float s = v.x * v.x + v.y * v.y + v.z * v.z + v.w * v.w;
  #pragma unroll
  for (int off = 32; off; off >>= 1) s += __shfl_down(s, off, 64);
  ushort4 b;
  b.x = f2bf(v.x); b.y = f2bf(v.y); b.z = f2bf(v.z); b.w = f2bf(v.w);
  *reinterpret_cast<ushort4*>(cb_bf + (size_t)k * 256 + lane * 4) = b;
  if (lane == 0) ee[k] = s;
}

// ---------------------------------------------------------------------------
// Main: 256 thr (4 waves), TOK=64, grid 512 -> 2 blocks/CU (LDS ~74.3 KB).
// R5 chassis (async dbuf global_load_lds, XOR granule swizzle, ILP epilogue)
// with a DS-FREE SCREEN. Conflict ledger: R5 shuffle-screen 4.4M, R8 atomic-
// screen 8.3M (neutral swap), R9 16-code atomic 18.1M (-39us). Both screen
// flavors are DS round-trips; this round REMOVES DS from the hot loop:
// per lane, per r-token, a sorted best-4 of packed (trunc22dist|code10) uints
// maintained in registers (7 min/max VALU per code, 16 VGPRs, no shuffles,
// no atomics, no admit branches). After the loop, ONCE: reduce b1 -> exact
// screen-min mhat; thr = mhat + 1.75 + 0.002*zn*enmax (1.5 >= 2eps screen
// bound, est. R0-R8; +0.25 trunc bound for d<2048); flag each lane's 4
// packs; ballot. n==1 -> winner = mhat's idx, no rescore (R1 two-tier).
// n>1 -> flagged packs -> cand + R5-ILP fp32 rescore (smallest-k tiebreak).
// Coverage proof: lane's discarded codes >= its b4; b4 > thr => covered;
// b4 <= thr (4 near-ties in ONE lane's 64 codes, ~never) -> ccnt+=1000 ->
// exact full-K fallback.
// DO NOT: 512-thread blocks (VGPR crush + spill); __launch_bounds__ 2nd arg
// >2 (R6: crushed to 52 VGPR); uint4 register prefetch arrays (R3 spill);
// MAXC<32 or looser margin (R2: 4x straggler); barrier-free L2 streaming
// (R7: 165us); wave-private 16-code chunks (R9: 18M conflicts, 145us).
// ---------------------------------------------------------------------------
__global__ __launch_bounds__(256, 2) void vq_main(
    const float* __restrict__ z, const float* __restrict__ cb,
    const unsigned short* __restrict__ cb_bf, const float* __restrict__ ee,
    const float* __restrict__ mask,
    float* __restrict__ out_q, float* __restrict__ out_idx_f,
    float* __restrict__ out_loss, float* __restrict__ acc2,
    int* __restrict__ done_ctr, int nblocks, int K) {
  __shared__ __align__(16) unsigned short sbuf[2 * BUFW];    // 64 KB: dbuf chunks; buf0 doubles as z-stage
  __shared__ float ee_lds[1024];                             // 4 KB
  __shared__ float znorm[TOK];
  __shared__ int   ccnt[TOK];
  __shared__ unsigned short cand[TOK * MAXC];                // 4 KB
  __shared__ unsigned short bkbuf[TOK];                      // winner index per token
  __shared__ float red[8];
  __shared__ bool  last;

  const int t = threadIdx.x;
  const int n0 = blockIdx.x * TOK;
  const int wv = t >> 6, lane = t & 63;
  const int quad = lane >> 4, l15 = lane & 15;
  const int q16 = t & 15;

  // ---- code norms into LDS + enmax partial ----
  float ea = ee[t], eb = ee[t + 256], ec = ee[t + 512], ed = ee[t + 768];
  ee_lds[t] = ea; ee_lds[t + 256] = eb; ee_lds[t + 512] = ec; ee_lds[t + 768] = ed;
  if (t < TOK) ccnt[t] = 0;
  float em = fmaxf(fmaxf(ea, eb), fmaxf(ec, ed));
  #pragma unroll
  for (int off = 32; off; off >>= 1) em = fmaxf(em, __shfl_xor(em, off, 64));
  if (lane == 0) red[wv] = em;

  // ---- stage z -> bf16 into buf0 rows 0..63 (swizzled); ||z|| ----
  #pragma unroll
  for (int pass = 0; pass < 4; ++pass) {
    int row = pass * 16 + (t >> 4);
    const float* zr = z + (size_t)(n0 + row) * 256;
    float ssq = 0.f;
    #pragma unroll
    for (int j = 0; j < 2; ++j) {
      float4 a = *reinterpret_cast<const float4*>(zr + q16 * 16 + j * 8);
      float4 b = *reinterpret_cast<const float4*>(zr + q16 * 16 + j * 8 + 4);
      ssq += a.x*a.x + a.y*a.y + a.z*a.z + a.w*a.w
           + b.x*b.x + b.y*b.y + b.z*b.z + b.w*b.w;
      int g = q16 * 2 + j;                       // logical granule 0..31
      *reinterpret_cast<uint4*>(&sbuf[row * 256 + ((g ^ (row & 7)) * 8)]) = pack8(a, b);
    }
    #pragma unroll
    for (int off = 1; off < 16; off <<= 1) ssq += __shfl_xor(ssq, off, 64);
    if (q16 == 0) znorm[row] = sqrtf(ssq);
  }
  __syncthreads();  // S1: z staged, red[] ready

  const float enmax = sqrtf(fmaxf(fmaxf(red[0], red[1]), fmaxf(red[2], red[3])));

  // ---- A fragments into registers: wave wv owns token rows wv*16 + l15 ----
  bf16x8 afrag[8];
  float  znreg[4];
  {
    int row = wv * 16 + l15;
    #pragma unroll
    for (int kk = 0; kk < 8; ++kk) {
      int g = (quad + kk * 4) ^ (row & 7);
      afrag[kk] = *reinterpret_cast<const bf16x8*>(&sbuf[row * 256 + g * 8]);
    }
    #pragma unroll
    for (int r = 0; r < 4; ++r)
      znreg[r] = znorm[wv * 16 + quad * 4 + r];
  }
  __syncthreads();  // S2: all A-loads done before chunk 0 overwrites buf0

  // ---- prologue: issue chunk 0 -> buf0 (async DMA), wait, publish ----
  {
    #pragma unroll
    for (int i = 0; i < 8; ++i) {
      int f = (wv * 8 + i) * 64 + lane;          // granule 0..2047
      int row = f >> 5, slot = f & 31;
      gload16(cb_bf + (size_t)row * 256 + ((slot ^ (row & 7)) * 8),
              &sbuf[(size_t)(wv * 512 + i * 64) * 8]);
    }
  }
  asm volatile("s_waitcnt vmcnt(0)" ::: "memory");
  __syncthreads();  // S3: chunk 0 visible

  // per-lane sorted best-4 packs per r-token (ascending)
  unsigned pk[4][4];
  #pragma unroll
  for (int r = 0; r < 4; ++r)
    #pragma unroll
    for (int j = 0; j < 4; ++j) pk[r][j] = 0x7F7FFFFFu;

  // ---- chunk loop: 16 chunks x 64 codes, double-buffered async staging ----
  for (int lc = 0; lc < NCH; ++lc) {
    const int kbase = lc * CH;
    unsigned short* cur = &sbuf[(lc & 1) * BUFW];
    unsigned short* nxt = &sbuf[((lc + 1) & 1) * BUFW];
    if (lc < NCH - 1) {  // issue next chunk's DMA before compute
      const unsigned short* base = cb_bf + (size_t)(kbase + CH) * 256;
      #pragma unroll
      for (int i = 0; i < 8; ++i) {
        int f = (wv * 8 + i) * 64 + lane;
        int row = f >> 5, slot = f & 31;
        gload16(base + (size_t)row * 256 + ((slot ^ (row & 7)) * 8),
                nxt + (size_t)(wv * 512 + i * 64) * 8);
      }
    }

    f32x4 acc[4];
    #pragma unroll
    for (int ct = 0; ct < 4; ++ct) acc[ct] = (f32x4){0.f, 0.f, 0.f, 0.f};
    __builtin_amdgcn_s_setprio(1);
    #pragma unroll
    for (int kk = 0; kk < 8; ++kk) {
      int gx = quad + kk * 4;
      bf16x8 b0 = *reinterpret_cast<const bf16x8*>(&cur[(l15)      * 256 + ((gx ^ ( l15       & 7)) * 8)]);
      bf16x8 b1 = *reinterpret_cast<const bf16x8*>(&cur[(16 + l15) * 256 + ((gx ^ ((16 + l15) & 7)) * 8)]);
      bf16x8 b2 = *reinterpret_cast<const bf16x8*>(&cur[(32 + l15) * 256 + ((gx ^ ((32 + l15) & 7)) * 8)]);
      bf16x8 b3 = *reinterpret_cast<const bf16x8*>(&cur[(48 + l15) * 256 + ((gx ^ ((48 + l15) & 7)) * 8)]);
      acc[0] = __builtin_amdgcn_mfma_f32_16x16x32_bf16(afrag[kk], b0, acc[0], 0, 0, 0);
      acc[1] = __builtin_amdgcn_mfma_f32_16x16x32_bf16(afrag[kk], b1, acc[1], 0, 0, 0);
      acc[2] = __builtin_amdgcn_mfma_f32_16x16x32_bf16(afrag[kk], b2, acc[2], 0, 0, 0);
      acc[3] = __builtin_amdgcn_mfma_f32_16x16x32_bf16(afrag[kk], b3, acc[3], 0, 0, 0);
    }
    __builtin_amdgcn_s_setprio(0);

    // DS-free screen: pure-VALU sorted-4 insert of packed (dist|code)
    float e0 = ee_lds[kbase + l15],      e1 = ee_lds[kbase + 16 + l15];
    float e2 = ee_lds[kbase + 32 + l15], e3 = ee_lds[kbase + 48 + l15];
    #pragma unroll
    for (int r = 0; r < 4; ++r) {
      float d0 = e0 - 2.f * acc[0][r];
      float d1 = e1 - 2.f * acc[1][r];
      float d2 = e2 - 2.f * acc[2][r];
      float d3 = e3 - 2.f * acc[3][r];
      unsigned pu, tt;
      #pragma unroll
      for (int ct = 0; ct < 4; ++ct) {
        float dd = (ct == 0) ? d0 : (ct == 1) ? d1 : (ct == 2) ? d2 : d3;
        pu = (__float_as_uint(fmaxf(dd, 0.f)) & 0xFFFFFC00u)
           | (unsigned)(kbase + ct * 16 + l15);
        tt = umn(pk[r][0], pu); pu = umx(pk[r][0], pu); pk[r][0] = tt;
        tt = umn(pk[r][1], pu); pu = umx(pk[r][1], pu); pk[r][1] = tt;
        tt = umn(pk[r][2], pu); pu = umx(pk[r][2], pu); pk[r][2] = tt;
        pk[r][3] = umn(pk[r][3], pu);
      }
    }
    asm volatile("s_waitcnt vmcnt(0)" ::: "memory");  // next-chunk DMA landed
    __syncthreads();                                  // visible to all waves
  }

  // ---- flags phase (ONCE): reduce b1, threshold, ballot, route ----
  #pragma unroll
  for (int r = 0; r < 4; ++r) {
    unsigned w = pk[r][0];
    #pragma unroll
    for (int off = 1; off < 16; off <<= 1)
      w = umn(w, (unsigned)__shfl_xor((int)w, off, 64));
    float mhat = __uint_as_float(w & 0xFFFFFC00u);
    float thr = mhat + 1.75f + 0.002f * znreg[r] * enmax;
    bool f0 = __uint_as_float(pk[r][0] & 0xFFFFFC00u) <= thr;
    bool f1 = __uint_as_float(pk[r][1] & 0xFFFFFC00u) <= thr;
    bool f2 = __uint_as_float(pk[r][2] & 0xFFFFFC00u) <= thr;
    bool f3 = __uint_as_float(pk[r][3] & 0xFFFFFC00u) <= thr;  // = coverage violated
    unsigned long long gm = 0xFFFFull << (quad << 4);
    int n = __popcll(__ballot(f0) & gm) + __popcll(__ballot(f1) & gm)
          + __popcll(__ballot(f2) & gm) + __popcll(__ballot(f3) & gm);
    int tok = wv * 16 + quad * 4 + r;
    if (n == 1) {
      if (l15 == 0) bkbuf[tok] = (unsigned short)(w & 1023u);  // unique candidate == argmin
    } else {
      if (f0) { int sl = atomicAdd(&ccnt[tok], 1); if (sl < MAXC) cand[tok * MAXC + sl] = (unsigned short)(pk[r][0] & 1023u); }
      if (f1) { int sl = atomicAdd(&ccnt[tok], 1); if (sl < MAXC) cand[tok * MAXC + sl] = (unsigned short)(pk[r][1] & 1023u); }
      if (f2) { int sl = atomicAdd(&ccnt[tok], 1); if (sl < MAXC) cand[tok * MAXC + sl] = (unsigned short)(pk[r][2] & 1023u); }
      if (f3) { atomicAdd(&ccnt[tok], 1000); }   // force exact full-K fallback
    }
  }
  // tokens are wave-private from here (flags, cand, rescore, outputs all by
  // the owning wave); same-wave DS ops are in-order -> no barrier needed.

  // ---- phase 1: exact fp32 rescore only where needed ----
  for (int it = 0; it < 16; ++it) {
    int tok = wv * 16 + it;
    int n = n0 + tok;
    int cnt = ccnt[tok];
    if (cnt == 0) continue;                      // winner already in bkbuf
    float4 zv = *reinterpret_cast<const float4*>(z + (size_t)n * 256 + lane * 4);
    float bs = 3.4e38f; int bk = 0;
    if (cnt > MAXC) {  // coverage-violation safety net: exact scan of all K
      for (int k = 0; k < K; k += 2) {
        float4 ca = *reinterpret_cast<const float4*>(cb + (size_t)k * 256 + lane * 4);
        float4 cbv = *reinterpret_cast<const float4*>(cb + (size_t)(k + 1) * 256 + lane * 4);
        float pa = zv.x * ca.x + zv.y * ca.y + zv.z * ca.z + zv.w * ca.w;
        float pb = zv.x * cbv.x + zv.y * cbv.y + zv.z * cbv.z + zv.w * cbv.w;
        #pragma unroll
        for (int off = 32; off; off >>= 1) {
          pa += __shfl_xor(pa, off, 64);
          pb += __shfl_xor(pb, off, 64);
        }
        float sa = ee_lds[k] - 2.f * pa;
        float sb = ee_lds[k + 1] - 2.f * pb;
        if (sa < bs) { bs = sa; bk = k; }
        if (sb < bs) { bs = sb; bk = k + 1; }
      }
    } else {
      bk = 1 << 29;
      int c = 0;
      for (; c + 4 <= cnt; c += 4) {
        int k0 = cand[tok * MAXC + c];
        int k1 = cand[tok * MAXC + c + 1];
        int k2 = cand[tok * MAXC + c + 2];
        int k3 = cand[tok * MAXC + c + 3];
        float4 e0 = *reinterpret_cast<const float4*>(cb + (size_t)k0 * 256 + lane * 4);
        float4 e1 = *reinterpret_cast<const float4*>(cb + (size_t)k1 * 256 + lane * 4);
        float4 e2 = *reinterpret_cast<const float4*>(cb + (size_t)k2 * 256 + lane * 4);
        float4 e3 = *reinterpret_cast<const float4*>(cb + (size_t)k3 * 256 + lane * 4);
        float p0 = zv.x * e0.x + zv.y * e0.y + zv.z * e0.z + zv.w * e0.w;
        float p1 = zv.x * e1.x + zv.y * e1.y + zv.z * e1.z + zv.w * e1.w;
        float p2 = zv.x * e2.x + zv.y * e2.y + zv.z * e2.z + zv.w * e2.w;
        float p3 = zv.x * e3.x + zv.y * e3.y + zv.z * e3.z + zv.w * e3.w;
        #pragma unroll
        for (int off = 32; off; off >>= 1) {
          p0 += __shfl_xor(p0, off, 64);
          p1 += __shfl_xor(p1, off, 64);
          p2 += __shfl_xor(p2, off, 64);
          p3 += __shfl_xor(p3, off, 64);
        }
        float s0 = ee_lds[k0] - 2.f * p0;
        float s1 = ee_lds[k1] - 2.f * p1;
        float s2 = ee_lds[k2] - 2.f * p2;
        float s3 = ee_lds[k3] - 2.f * p3;
        if (s0 < bs || (s0 == bs && k0 < bk)) { bs = s0; bk = k0; }
        if (s1 < bs || (s1 == bs && k1 < bk)) { bs = s1; bk = k1; }
        if (s2 < bs || (s2 == bs && k2 < bk)) { bs = s2; bk = k2; }
        if (s3 < bs || (s3 == bs && k3 < bk)) { bs = s3; bk = k3; }
      }
      for (; c < cnt; ++c) {
        int k = cand[tok * MAXC + c];
        float4 ev = *reinterpret_cast<const float4*>(cb + (size_t)k * 256 + lane * 4);
        float dp = zv.x * ev.x + zv.y * ev.y + zv.z * ev.z + zv.w * ev.w;
        #pragma unroll
        for (int off = 32; off; off >>= 1) dp += __shfl_xor(dp, off, 64);
        float s = ee_lds[k] - 2.f * dp;   // identical on all lanes
        if (s < bs || (s == bs && k < bk)) { bs = s; bk = k; }
      }
    }
    bkbuf[tok] = (unsigned short)bk;
  }

  // ---- phase 2: outputs + loss, 2 tokens in flight ----
  float lsum = 0.f, msum = 0.f;
  for (int it = 0; it < 16; it += 2) {
    int tokA = wv * 16 + it, tokB = tokA + 1;
    int na = n0 + tokA, nb = n0 + tokB;
    int ba = bkbuf[tokA], bb = bkbuf[tokB];
    float4 za = *reinterpret_cast<const float4*>(z + (size_t)na * 256 + lane * 4);
    float4 zb = *reinterpret_cast<const float4*>(z + (size_t)nb * 256 + lane * 4);
    float4 qa = *reinterpret_cast<const float4*>(cb + (size_t)ba * 256 + lane * 4);
    float4 qb = *reinterpret_cast<const float4*>(cb + (size_t)bb * 256 + lane * 4);
    float ma = mask[na], mb = mask[nb];
    float4 oa; oa.x = qa.x * ma; oa.y = qa.y * ma; oa.z = qa.z * ma; oa.w = qa.w * ma;
    float4 ob; ob.x = qb.x * mb; ob.y = qb.y * mb; ob.z = qb.z * mb; ob.w = qb.w * mb;
    *reinterpret_cast<float4*>(out_q + (size_t)na * 256 + lane * 4) = oa;
    *reinterpret_cast<float4*>(out_q + (size_t)nb * 256 + lane * 4) = ob;
    float dxa = za.x - qa.x, dya = za.y - qa.y, dza = za.z - qa.z, dwa = za.w - qa.w;
    float dxb = zb.x - qb.x, dyb = zb.y - qb.y, dzb = zb.z - qb.z, dwb = zb.w - qb.w;
    lsum = fmaf(ma, dxa * dxa + dya * dya + dza * dza + dwa * dwa, lsum);
    lsum = fmaf(mb, dxb * dxb + dyb * dyb + dzb * dzb + dwb * dwb, lsum);
    if (lane == 0) {
      msum += ma + mb;
      out_idx_f[na] = (ma > 0.f) ? (float)ba : 0.f;
      out_idx_f[nb] = (mb > 0.f) ? (float)bb : 0.f;
    }
  }
  #pragma unroll
  for (int off = 32; off; off >>= 1) lsum += __shfl_down(lsum, off, 64);
  if (lane == 0) { red[wv] = lsum; red[4 + wv] = msum; }
  __syncthreads();
  if (t == 0) {
    atomicAdd(&acc2[0], red[0] + red[1] + red[2] + red[3]);
    atomicAdd(&acc2[1], red[4] + red[5] + red[6] + red[7]);
    __threadfence();
    int prev = atomicAdd(done_ctr, 1);
    last = (prev == nblocks - 1);
  }
  __syncthreads();
  if (last && t == 0) {
    float s  = atomicAdd(&acc2[0], 0.0f);
    float nv = atomicAdd(&acc2[1], 0.0f);
    out_loss[0] = (nv > 0.f) ? (0.25f * s / (nv * 256.0f)) : 0.0f;
  }
}

// ---------------------------------------------------------------------------
extern "C" void kernel_launch(void* const* d_in, const int* in_sizes, int n_in,
                              void* d_out, int out_size, void* d_ws, size_t ws_size,
                              hipStream_t stream) {
  const float* z    = (const float*)d_in[0];  // (N, 256)
  const float* mask = (const float*)d_in[1];  // (N,)
  const float* cb   = (const float*)d_in[2];  // (K, 256)
  const int N = in_sizes[1];                  // 32768
  const int D = 256;
  const int K = in_sizes[2] / D;              // 1024

  float* wsf  = (float*)d_ws;
  float* acc2 = wsf;                          // 2 floats
  int*   dctr = (int*)(wsf + 2);              // 1 int
  float* ee   = wsf + 8;                      // K floats
  unsigned short* cb_bf = (unsigned short*)(ee + K);  // K*256 bf16

  float* out_q     = (float*)d_out;           // N*D
  float* out_loss  = out_q + (size_t)N * D;   // 1
  float* out_idx_f = out_loss + 1;            // N

  vq_prep<<<(K + 3) / 4, 256, 0, stream>>>(cb, cb_bf, ee, acc2, dctr, K);
  vq_main<<<N / TOK, 256, 0, stream>>>(z, cb, cb_bf, ee, mask, out_q,
                                       out_idx_f, out_loss, acc2, dctr, N / TOK, K);
}

// Round 11
// 164.983 us; speedup vs baseline: 2.1331x; 2.1331x over previous
//
#include <hip/hip_runtime.h>
#include <cstdint>

typedef short bf16x8 __attribute__((ext_vector_type(8)));
typedef float f32x4  __attribute__((ext_vector_type(4)));

#define TOK    64         // tokens per block
#define CH     64         // codes per chunk
#define NCH    16         // chunks (K=1024)
#define BUFW   16384      // ushorts per chunk buffer (64 rows x 256)
#define MAXC   32

__device__ __forceinline__ unsigned short f2bf(float f) {
  unsigned u = __float_as_uint(f);
  return (unsigned short)((u + 0x7FFFu + ((u >> 16) & 1u)) >> 16);
}
__device__ __forceinline__ uint4 pack8(float4 a, float4 b) {
  uint4 u;
  u.x = (unsigned)f2bf(a.x) | ((unsigned)f2bf(a.y) << 16);
  u.y = (unsigned)f2bf(a.z) | ((unsigned)f2bf(a.w) << 16);
  u.z = (unsigned)f2bf(b.x) | ((unsigned)f2bf(b.y) << 16);
  u.w = (unsigned)f2bf(b.z) | ((unsigned)f2bf(b.w) << 16);
  return u;
}
// async global->LDS DMA, 16 B per lane. LDS dest = wave-uniform base + lane*16.
__device__ __forceinline__ void gload16(const unsigned short* g, unsigned short* l) {
  __builtin_amdgcn_global_load_lds(
      (const __attribute__((address_space(1))) unsigned int*)(const void*)g,
      (__attribute__((address_space(3))) unsigned int*)(void*)l, 16, 0, 0);
}

// ---------------------------------------------------------------------------
// Prep: cb_bf = bf16(cb), ee = ||cb_k||^2. Block 0 zeroes global accumulators.
// ---------------------------------------------------------------------------
__global__ __launch_bounds__(256) void vq_prep(const float* __restrict__ cb,
                                               unsigned short* __restrict__ cb_bf,
                                               float* __restrict__ ee,
                                               float* __restrict__ acc2,
                                               int* __restrict__ done_ctr, int K) {
  if (blockIdx.x == 0 && threadIdx.x == 0) {
    acc2[0] = 0.f; acc2[1] = 0.f; *done_ctr = 0;
  }
  int wave = threadIdx.x >> 6, lane = threadIdx.x & 63;
  int k = blockIdx.x * 4 + wave;
  if (k >= K) return;
  float4 v = *reinterpret_cast<const float4*>(cb + (size_t)k * 256 + lane * 4);
  float s = v.x * v.x + v.y * v.y + v.z * v.z + v.w * v.w;
  #pragma unroll
  for (int off = 32; off; off >>= 1) s += __shfl_down(s, off, 64);
  ushort4 b;
  b.x = f2bf(v.x); b.y = f2bf(v.y); b.z = f2bf(v.z); b.w = f2bf(v.w);
  *reinterpret_cast<ushort4*>(cb_bf + (size_t)k * 256 + lane * 4) = b;
  if (lane == 0) ee[k] = s;
}

// ---------------------------------------------------------------------------
// Main: 256 thr (4 waves), TOK=64, grid 512 -> 2 blocks/CU (LDS ~78.8 KB).
// R8 chassis VERBATIM in the hot loop (async dbuf global_load_lds staging,
// XOR granule swizzle, atomicMin umin gate = measured 106 us, neutral vs R5).
// R11 change is EPILOGUE-ONLY (the one region where a predicted win has ever
// landed, R5 -25us): cand stores packed (trunc22 dist | idx10); phase 1 flags
// candidates against thr = umin + 1.5 + 0.002*zn*enmax with one ballot; if
// exactly ONE candidate is flagged it IS the exact argmin (containment:
// dhat(k*) <= umin + 2eps <= thr, truncation only lowers pe -> k* always
// flagged; fp32 ties put both in the flagged set -> rescore path keeps the
// smallest-k tiebreak) -> skip the rescore dots AND the zv load. n>1 ->
// R5's proven 4-way-unrolled rescore over all cnt. Overflow path unchanged.
// DO NOT: 512-thread blocks (VGPR crush + spill); __launch_bounds__ 2nd arg
// >2 (R6: crushed to 52 VGPR); uint4 register prefetch arrays (R3 spill);
// MAXC<32 or looser margin (R2: 4x straggler); barrier-free L2 streaming
// (R7: 165us); wave-private 16-code chunks (R9: 18M conflicts, 145us);
// big unrolled register-sort screens in the hot loop (R10: uniform 2.7x
// slowdown, suspected L1I blowup -- keep the loop body compact).
// ---------------------------------------------------------------------------
__global__ __launch_bounds__(256, 2) void vq_main(
    const float* __restrict__ z, const float* __restrict__ cb,
    const unsigned short* __restrict__ cb_bf, const float* __restrict__ ee,
    const float* __restrict__ mask,
    float* __restrict__ out_q, float* __restrict__ out_idx_f,
    float* __restrict__ out_loss, float* __restrict__ acc2,
    int* __restrict__ done_ctr, int nblocks, int K) {
  __shared__ __align__(16) unsigned short sbuf[2 * BUFW];    // 64 KB: dbuf chunks; buf0 doubles as z-stage
  __shared__ float ee_lds[1024];                             // 4 KB
  __shared__ float znorm[TOK];
  __shared__ int   ccnt[TOK];
  __shared__ unsigned umin[TOK];                             // packed float gate (nonneg -> uint order)
  __shared__ unsigned cand[TOK * MAXC];                      // 8 KB packed (dist22|idx10)
  __shared__ unsigned short bkbuf[TOK];                      // winner index per token
  __shared__ float red[8];
  __shared__ bool  last;

  const int t = threadIdx.x;
  const int n0 = blockIdx.x * TOK;
  const int wv = t >> 6, lane = t & 63;
  const int quad = lane >> 4, l15 = lane & 15;
  const int q16 = t & 15;

  // ---- code norms into LDS + enmax partial ----
  float ea = ee[t], eb = ee[t + 256], ec = ee[t + 512], ed = ee[t + 768];
  ee_lds[t] = ea; ee_lds[t + 256] = eb; ee_lds[t + 512] = ec; ee_lds[t + 768] = ed;
  if (t < TOK) { ccnt[t] = 0; umin[t] = 0x7F7FFFFFu; }
  float em = fmaxf(fmaxf(ea, eb), fmaxf(ec, ed));
  #pragma unroll
  for (int off = 32; off; off >>= 1) em = fmaxf(em, __shfl_xor(em, off, 64));
  if (lane == 0) red[wv] = em;

  // ---- stage z -> bf16 into buf0 rows 0..63 (swizzled); ||z|| ----
  #pragma unroll
  for (int pass = 0; pass < 4; ++pass) {
    int row = pass * 16 + (t >> 4);
    const float* zr = z + (size_t)(n0 + row) * 256;
    float ssq = 0.f;
    #pragma unroll
    for (int j = 0; j < 2; ++j) {
      float4 a = *reinterpret_cast<const float4*>(zr + q16 * 16 + j * 8);
      float4 b = *reinterpret_cast<const float4*>(zr + q16 * 16 + j * 8 + 4);
      ssq += a.x*a.x + a.y*a.y + a.z*a.z + a.w*a.w
           + b.x*b.x + b.y*b.y + b.z*b.z + b.w*b.w;
      int g = q16 * 2 + j;                       // logical granule 0..31
      *reinterpret_cast<uint4*>(&sbuf[row * 256 + ((g ^ (row & 7)) * 8)]) = pack8(a, b);
    }
    #pragma unroll
    for (int off = 1; off < 16; off <<= 1) ssq += __shfl_xor(ssq, off, 64);
    if (q16 == 0) znorm[row] = sqrtf(ssq);
  }
  __syncthreads();  // S1: z staged, red[] ready

  const float enmax = sqrtf(fmaxf(fmaxf(red[0], red[1]), fmaxf(red[2], red[3])));

  // ---- A fragments into registers: wave wv owns token rows wv*16 + l15 ----
  bf16x8 afrag[8];
  float  znreg[4];
  {
    int row = wv * 16 + l15;
    #pragma unroll
    for (int kk = 0; kk < 8; ++kk) {
      int g = (quad + kk * 4) ^ (row & 7);
      afrag[kk] = *reinterpret_cast<const bf16x8*>(&sbuf[row * 256 + g * 8]);
    }
    #pragma unroll
    for (int r = 0; r < 4; ++r)
      znreg[r] = znorm[wv * 16 + quad * 4 + r];
  }
  __syncthreads();  // S2: all A-loads done before chunk 0 overwrites buf0

  // ---- prologue: issue chunk 0 -> buf0 (async DMA), wait, publish ----
  {
    #pragma unroll
    for (int i = 0; i < 8; ++i) {
      int f = (wv * 8 + i) * 64 + lane;          // granule 0..2047
      int row = f >> 5, slot = f & 31;
      gload16(cb_bf + (size_t)row * 256 + ((slot ^ (row & 7)) * 8),
              &sbuf[(size_t)(wv * 512 + i * 64) * 8]);
    }
  }
  asm volatile("s_waitcnt vmcnt(0)" ::: "memory");
  __syncthreads();  // S3: chunk 0 visible

  // ---- chunk loop: 16 chunks x 64 codes, double-buffered async staging ----
  for (int lc = 0; lc < NCH; ++lc) {
    const int kbase = lc * CH;
    unsigned short* cur = &sbuf[(lc & 1) * BUFW];
    unsigned short* nxt = &sbuf[((lc + 1) & 1) * BUFW];
    if (lc < NCH - 1) {  // issue next chunk's DMA before compute
      const unsigned short* base = cb_bf + (size_t)(kbase + CH) * 256;
      #pragma unroll
      for (int i = 0; i < 8; ++i) {
        int f = (wv * 8 + i) * 64 + lane;
        int row = f >> 5, slot = f & 31;
        gload16(base + (size_t)row * 256 + ((slot ^ (row & 7)) * 8),
                nxt + (size_t)(wv * 512 + i * 64) * 8);
      }
    }

    f32x4 acc[4];
    #pragma unroll
    for (int ct = 0; ct < 4; ++ct) acc[ct] = (f32x4){0.f, 0.f, 0.f, 0.f};
    __builtin_amdgcn_s_setprio(1);
    #pragma unroll
    for (int kk = 0; kk < 8; ++kk) {
      int gx = quad + kk * 4;
      bf16x8 b0 = *reinterpret_cast<const bf16x8*>(&cur[(l15)      * 256 + ((gx ^ ( l15       & 7)) * 8)]);
      bf16x8 b1 = *reinterpret_cast<const bf16x8*>(&cur[(16 + l15) * 256 + ((gx ^ ((16 + l15) & 7)) * 8)]);
      bf16x8 b2 = *reinterpret_cast<const bf16x8*>(&cur[(32 + l15) * 256 + ((gx ^ ((32 + l15) & 7)) * 8)]);
      bf16x8 b3 = *reinterpret_cast<const bf16x8*>(&cur[(48 + l15) * 256 + ((gx ^ ((48 + l15) & 7)) * 8)]);
      acc[0] = __builtin_amdgcn_mfma_f32_16x16x32_bf16(afrag[kk], b0, acc[0], 0, 0, 0);
      acc[1] = __builtin_amdgcn_mfma_f32_16x16x32_bf16(afrag[kk], b1, acc[1], 0, 0, 0);
      acc[2] = __builtin_amdgcn_mfma_f32_16x16x32_bf16(afrag[kk], b2, acc[2], 0, 0, 0);
      acc[3] = __builtin_amdgcn_mfma_f32_16x16x32_bf16(afrag[kk], b3, acc[3], 0, 0, 0);
    }
    __builtin_amdgcn_s_setprio(0);

    float e0 = ee_lds[kbase + l15],      e1 = ee_lds[kbase + 16 + l15];
    float e2 = ee_lds[kbase + 32 + l15], e3 = ee_lds[kbase + 48 + l15];
    float en0 = sqrtf(e0), en1 = sqrtf(e1), en2 = sqrtf(e2), en3 = sqrtf(e3);
    #pragma unroll
    for (int r = 0; r < 4; ++r) {
      float d0 = e0 - 2.f * acc[0][r];
      float d1 = e1 - 2.f * acc[1][r];
      float d2 = e2 - 2.f * acc[2][r];
      float d3 = e3 - 2.f * acc[3][r];
      int tok = wv * 16 + quad * 4 + r;
      // publish this lane's chunk-min, then read the gate back (same-wave DS
      // in-order): gate == 16-lane group min plus all earlier publishes.
      float dm = fmaxf(fminf(fminf(d0, d1), fminf(d2, d3)), 0.f);
      atomicMin(&umin[tok], __float_as_uint(dm));
      float am = __uint_as_float(umin[tok]);
      float zn = znreg[r];
      // margin >= 2*eps(bf16 screen); published-gate keeps the bound
      if (d0 <= am + 1.5f + 0.002f * zn * en0) {
        int sl = atomicAdd(&ccnt[tok], 1);
        if (sl < MAXC) cand[tok * MAXC + sl] =
            (__float_as_uint(fmaxf(d0, 0.f)) & 0xFFFFFC00u) | (unsigned)(kbase + l15);
      }
      if (d1 <= am + 1.5f + 0.002f * zn * en1) {
        int sl = atomicAdd(&ccnt[tok], 1);
        if (sl < MAXC) cand[tok * MAXC + sl] =
            (__float_as_uint(fmaxf(d1, 0.f)) & 0xFFFFFC00u) | (unsigned)(kbase + 16 + l15);
      }
      if (d2 <= am + 1.5f + 0.002f * zn * en2) {
        int sl = atomicAdd(&ccnt[tok], 1);
        if (sl < MAXC) cand[tok * MAXC + sl] =
            (__float_as_uint(fmaxf(d2, 0.f)) & 0xFFFFFC00u) | (unsigned)(kbase + 32 + l15);
      }
      if (d3 <= am + 1.5f + 0.002f * zn * en3) {
        int sl = atomicAdd(&ccnt[tok], 1);
        if (sl < MAXC) cand[tok * MAXC + sl] =
            (__float_as_uint(fmaxf(d3, 0.f)) & 0xFFFFFC00u) | (unsigned)(kbase + 48 + l15);
      }
    }
    asm volatile("s_waitcnt vmcnt(0)" ::: "memory");  // next-chunk DMA landed
    __syncthreads();                                  // visible to all waves
  }

  // ---- phase 1: two-tier exact rescore (tokens are wave-private) ----
  for (int it = 0; it < 16; ++it) {
    int tok = wv * 16 + it;
    int n = n0 + tok;
    int cnt = ccnt[tok];
    int bk = 0;
    if (cnt > MAXC) {  // overflow safety net: exact scan of all K, 2-unrolled
      float4 zv = *reinterpret_cast<const float4*>(z + (size_t)n * 256 + lane * 4);
      float bs = 3.4e38f;
      for (int k = 0; k < K; k += 2) {
        float4 ca = *reinterpret_cast<const float4*>(cb + (size_t)k * 256 + lane * 4);
        float4 cbv = *reinterpret_cast<const float4*>(cb + (size_t)(k + 1) * 256 + lane * 4);
        float pa = zv.x * ca.x + zv.y * ca.y + zv.z * ca.z + zv.w * ca.w;
        float pb = zv.x * cbv.x + zv.y * cbv.y + zv.z * cbv.z + zv.w * cbv.w;
        #pragma unroll
        for (int off = 32; off; off >>= 1) {
          pa += __shfl_xor(pa, off, 64);
          pb += __shfl_xor(pb, off, 64);
        }
        float sa = ee_lds[k] - 2.f * pa;
        float sb = ee_lds[k + 1] - 2.f * pb;
        if (sa < bs) { bs = sa; bk = k; }
        if (sb < bs) { bs = sb; bk = k + 1; }
      }
    } else {
      // tier 1: flag candidates within margin of the exact screen-min
      float thr = __uint_as_float(umin[tok]) + 1.5f + 0.002f * znorm[tok] * enmax;
      int c = (lane < cnt) ? lane : 0;
      unsigned pe = cand[tok * MAXC + c];
      bool flag = (lane < cnt) && (__uint_as_float(pe & 0xFFFFFC00u) <= thr);
      unsigned long long msk = __ballot(flag);
      if (__popcll(msk) == 1) {
        int cc = __ffsll((long long)msk) - 1;
        bk = (int)(cand[tok * MAXC + cc] & 1023u);   // unique in-margin == argmin
      } else {
        // tier 2: R5's 4-way-unrolled exact fp32 rescore over all cnt
        float4 zv = *reinterpret_cast<const float4*>(z + (size_t)n * 256 + lane * 4);
        float bs = 3.4e38f; bk = 1 << 29;
        int cc = 0;
        for (; cc + 4 <= cnt; cc += 4) {
          int k0 = cand[tok * MAXC + cc]     & 1023;
          int k1 = cand[tok * MAXC + cc + 1] & 1023;
          int k2 = cand[tok * MAXC + cc + 2] & 1023;
          int k3 = cand[tok * MAXC + cc + 3] & 1023;
          float4 e0 = *reinterpret_cast<const float4*>(cb + (size_t)k0 * 256 + lane * 4);
          float4 e1 = *reinterpret_cast<const float4*>(cb + (size_t)k1 * 256 + lane * 4);
          float4 e2 = *reinterpret_cast<const float4*>(cb + (size_t)k2 * 256 + lane * 4);
          float4 e3 = *reinterpret_cast<const float4*>(cb + (size_t)k3 * 256 + lane * 4);
          float p0 = zv.x * e0.x + zv.y * e0.y + zv.z * e0.z + zv.w * e0.w;
          float p1 = zv.x * e1.x + zv.y * e1.y + zv.z * e1.z + zv.w * e1.w;
          float p2 = zv.x * e2.x + zv.y * e2.y + zv.z * e2.z + zv.w * e2.w;
          float p3 = zv.x * e3.x + zv.y * e3.y + zv.z * e3.z + zv.w * e3.w;
          #pragma unroll
          for (int off = 32; off; off >>= 1) {   // 4 independent reduce chains
            p0 += __shfl_xor(p0, off, 64);
            p1 += __shfl_xor(p1, off, 64);
            p2 += __shfl_xor(p2, off, 64);
            p3 += __shfl_xor(p3, off, 64);
          }
          float s0 = ee_lds[k0] - 2.f * p0;
          float s1 = ee_lds[k1] - 2.f * p1;
          float s2 = ee_lds[k2] - 2.f * p2;
          float s3 = ee_lds[k3] - 2.f * p3;
          if (s0 < bs || (s0 == bs && k0 < bk)) { bs = s0; bk = k0; }
          if (s1 < bs || (s1 == bs && k1 < bk)) { bs = s1; bk = k1; }
          if (s2 < bs || (s2 == bs && k2 < bk)) { bs = s2; bk = k2; }
          if (s3 < bs || (s3 == bs && k3 < bk)) { bs = s3; bk = k3; }
        }
        for (; cc < cnt; ++cc) {
          int k = cand[tok * MAXC + cc] & 1023;
          float4 ev = *reinterpret_cast<const float4*>(cb + (size_t)k * 256 + lane * 4);
          float dp = zv.x * ev.x + zv.y * ev.y + zv.z * ev.z + zv.w * ev.w;
          #pragma unroll
          for (int off = 32; off; off >>= 1) dp += __shfl_xor(dp, off, 64);
          float s = ee_lds[k] - 2.f * dp;   // identical on all lanes
          if (s < bs || (s == bs && k < bk)) { bs = s; bk = k; }
        }
      }
    }
    bkbuf[tok] = (unsigned short)bk;
  }

  // ---- phase 2: outputs + loss, 2 tokens in flight ----
  float lsum = 0.f, msum = 0.f;
  for (int it = 0; it < 16; it += 2) {
    int tokA = wv * 16 + it, tokB = tokA + 1;
    int na = n0 + tokA, nb = n0 + tokB;
    int ba = bkbuf[tokA], bb = bkbuf[tokB];
    float4 za = *reinterpret_cast<const float4*>(z + (size_t)na * 256 + lane * 4);
    float4 zb = *reinterpret_cast<const float4*>(z + (size_t)nb * 256 + lane * 4);
    float4 qa = *reinterpret_cast<const float4*>(cb + (size_t)ba * 256 + lane * 4);
    float4 qb = *reinterpret_cast<const float4*>(cb + (size_t)bb * 256 + lane * 4);
    float ma = mask[na], mb = mask[nb];
    float4 oa; oa.x = qa.x * ma; oa.y = qa.y * ma; oa.z = qa.z * ma; oa.w = qa.w * ma;
    float4 ob; ob.x = qb.x * mb; ob.y = qb.y * mb; ob.z = qb.z * mb; ob.w = qb.w * mb;
    *reinterpret_cast<float4*>(out_q + (size_t)na * 256 + lane * 4) = oa;
    *reinterpret_cast<float4*>(out_q + (size_t)nb * 256 + lane * 4) = ob;
    float dxa = za.x - qa.x, dya = za.y - qa.y, dza = za.z - qa.z, dwa = za.w - qa.w;
    float dxb = zb.x - qb.x, dyb = zb.y - qb.y, dzb = zb.z - qb.z, dwb = zb.w - qb.w;
    lsum = fmaf(ma, dxa * dxa + dya * dya + dza * dza + dwa * dwa, lsum);
    lsum = fmaf(mb, dxb * dxb + dyb * dyb + dzb * dzb + dwb * dwb, lsum);
    if (lane == 0) {
      msum += ma + mb;
      out_idx_f[na] = (ma > 0.f) ? (float)ba : 0.f;
      out_idx_f[nb] = (mb > 0.f) ? (float)bb : 0.f;
    }
  }
  #pragma unroll
  for (int off = 32; off; off >>= 1) lsum += __shfl_down(lsum, off, 64);
  if (lane == 0) { red[wv] = lsum; red[4 + wv] = msum; }
  __syncthreads();
  if (t == 0) {
    atomicAdd(&acc2[0], red[0] + red[1] + red[2] + red[3]);
    atomicAdd(&acc2[1], red[4] + red[5] + red[6] + red[7]);
    __threadfence();
    int prev = atomicAdd(done_ctr, 1);
    last = (prev == nblocks - 1);
  }
  __syncthreads();
  if (last && t == 0) {
    float s  = atomicAdd(&acc2[0], 0.0f);
    float nv = atomicAdd(&acc2[1], 0.0f);
    out_loss[0] = (nv > 0.f) ? (0.25f * s / (nv * 256.0f)) : 0.0f;
  }
}

// ---------------------------------------------------------------------------
extern "C" void kernel_launch(void* const* d_in, const int* in_sizes, int n_in,
                              void* d_out, int out_size, void* d_ws, size_t ws_size,
                              hipStream_t stream) {
  const float* z    = (const float*)d_in[0];  // (N, 256)
  const float* mask = (const float*)d_in[1];  // (N,)
  const float* cb   = (const float*)d_in[2];  // (K, 256)
  const int N = in_sizes[1];                  // 32768
  const int D = 256;
  const int K = in_sizes[2] / D;              // 1024

  float* wsf  = (float*)d_ws;
  float* acc2 = wsf;                          // 2 floats
  int*   dctr = (int*)(wsf + 2);              // 1 int
  float* ee   = wsf + 8;                      // K floats
  unsigned short* cb_bf = (unsigned short*)(ee + K);  // K*256 bf16

  float* out_q     = (float*)d_out;           // N*D
  float* out_loss  = out_q + (size_t)N * D;   // 1
  float* out_idx_f = out_loss + 1;            // N

  vq_prep<<<(K + 3) / 4, 256, 0, stream>>>(cb, cb_bf, ee, acc2, dctr, K);
  vq_main<<<N / TOK, 256, 0, stream>>>(z, cb, cb_bf, ee, mask, out_q,
                                       out_idx_f, out_loss, acc2, dctr, N / TOK, K);
}

// Round 12
// 162.186 us; speedup vs baseline: 2.1699x; 1.0172x over previous
//
#include <hip/hip_runtime.h>
#include <cstdint>

typedef short bf16x8 __attribute__((ext_vector_type(8)));
typedef float f32x16 __attribute__((ext_vector_type(16)));

#define TOK    64         // tokens per block
#define CH     64         // codes per chunk
#define NCH    16         // chunks (K=1024)
#define BUFW   16384      // ushorts per chunk buffer (64 rows x 256)
#define MAXC   32

__device__ __forceinline__ unsigned short f2bf(float f) {
  unsigned u = __float_as_uint(f);
  return (unsigned short)((u + 0x7FFFu + ((u >> 16) & 1u)) >> 16);
}
__device__ __forceinline__ uint4 pack8(float4 a, float4 b) {
  uint4 u;
  u.x = (unsigned)f2bf(a.x) | ((unsigned)f2bf(a.y) << 16);
  u.y = (unsigned)f2bf(a.z) | ((unsigned)f2bf(a.w) << 16);
  u.z = (unsigned)f2bf(b.x) | ((unsigned)f2bf(b.y) << 16);
  u.w = (unsigned)f2bf(b.z) | ((unsigned)f2bf(b.w) << 16);
  return u;
}
// async global->LDS DMA, 16 B per lane. LDS dest = wave-uniform base + lane*16.
__device__ __forceinline__ void gload16(const unsigned short* g, unsigned short* l) {
  __builtin_amdgcn_global_load_lds(
      (const __attribute__((address_space(1))) unsigned int*)(const void*)g,
      (__attribute__((address_space(3))) unsigned int*)(void*)l, 16, 0, 0);
}

// ---------------------------------------------------------------------------
// Prep: cb_bf = bf16(cb), ee = ||cb_k||^2. Block 0 zeroes global accumulators.
// ---------------------------------------------------------------------------
__global__ __launch_bounds__(256) void vq_prep(const float* __restrict__ cb,
                                               unsigned short* __restrict__ cb_bf,
                                               float* __restrict__ ee,
                                               float* __restrict__ acc2,
                                               int* __restrict__ done_ctr, int K) {
  if (blockIdx.x == 0 && threadIdx.x == 0) {
    acc2[0] = 0.f; acc2[1] = 0.f; *done_ctr = 0;
  }
  int wave = threadIdx.x >> 6, lane = threadIdx.x & 63;
  int k = blockIdx.x * 4 + wave;
  if (k >= K) return;
  float4 v = *reinterpret_cast<const float4*>(cb + (size_t)k * 256 + lane * 4);
  float s = v.x * v.x + v.y * v.y + v.z * v.z + v.w * v.w;
  #pragma unroll
  for (int off = 32; off; off >>= 1) s += __shfl_down(s, off, 64);
  ushort4 b;
  b.x = f2bf(v.x); b.y = f2bf(v.y); b.z = f2bf(v.z); b.w = f2bf(v.w);
  *reinterpret_cast<ushort4*>(cb_bf + (size_t)k * 256 + lane * 4) = b;
  if (lane == 0) ee[k] = s;
}

// ---------------------------------------------------------------------------
// Main: 256 thr (4 waves), TOK=64, grid 512 -> 2 blocks/CU (LDS ~78 KB).
// R11 chassis with the hot loop retiled to mfma_f32_32x32x16_bf16:
// wave (ts=wv&1 token-tile, cs=wv>>1 code-tile) computes 32 tokens x 32
// codes per chunk: 16 MFMAs, tokens in registers (tfrag[16], 64 VGPR), codes
// streamed from LDS (16 ds_read_b128/chunk, HALF of R11's 32). C/D layout
// (HW-verified): col=lane&31 = TOKEN, row=(reg&3)+8*(reg>>2)+4*(lane>>5) =
// CODE -> each lane holds 16 codes of ONE token -> screen is 16 register
// fmins + ONE 2-way atomicMin + ONE gate read per chunk (R11: 4x 16-way
// atomic + 4 reads serialized ~1-2k cy/chunk -- the largest unhidden DS
// block; also explains R8 neutrality and R9's regression). Admission checks
// guarded by the loose enmax bound so most lanes skip them. Margin logic,
// staging DMA, two-tier epilogue: R11 VERBATIM.
// DO NOT: 512-thread blocks (VGPR crush + spill); __launch_bounds__ 2nd arg
// >2 (R6: crushed to 52 VGPR); uint4 register prefetch arrays (R3 spill);
// MAXC<32 or looser margin (R2: 4x straggler); barrier-free L2 streaming
// (R7); wave-private 16-code chunks (R9); big unrolled register-sort screens
// (R10: I$ blowup).
// ---------------------------------------------------------------------------
__global__ __launch_bounds__(256, 2) void vq_main(
    const float* __restrict__ z, const float* __restrict__ cb,
    const unsigned short* __restrict__ cb_bf, const float* __restrict__ ee,
    const float* __restrict__ mask,
    float* __restrict__ out_q, float* __restrict__ out_idx_f,
    float* __restrict__ out_loss, float* __restrict__ acc2,
    int* __restrict__ done_ctr, int nblocks, int K) {
  __shared__ __align__(16) unsigned short sbuf[2 * BUFW];    // 64 KB: dbuf chunks; buf0 doubles as z-stage
  __shared__ float ee_lds[1024];                             // 4 KB
  __shared__ float znorm[TOK];
  __shared__ int   ccnt[TOK];
  __shared__ unsigned umin[TOK];                             // packed float gate (nonneg -> uint order)
  __shared__ unsigned cand[TOK * MAXC];                      // 8 KB packed (dist22|idx10)
  __shared__ unsigned short bkbuf[TOK];                      // winner index per token
  __shared__ float red[8];
  __shared__ bool  last;

  const int t = threadIdx.x;
  const int n0 = blockIdx.x * TOK;
  const int wv = t >> 6, lane = t & 63;
  const int ts = wv & 1, cs = wv >> 1;
  const int l31 = lane & 31, hk = lane >> 5;
  const int q16 = t & 15;

  // ---- code norms into LDS + enmax partial ----
  float ea = ee[t], eb = ee[t + 256], ec = ee[t + 512], ed = ee[t + 768];
  ee_lds[t] = ea; ee_lds[t + 256] = eb; ee_lds[t + 512] = ec; ee_lds[t + 768] = ed;
  if (t < TOK) { ccnt[t] = 0; umin[t] = 0x7F7FFFFFu; }
  float em = fmaxf(fmaxf(ea, eb), fmaxf(ec, ed));
  #pragma unroll
  for (int off = 32; off; off >>= 1) em = fmaxf(em, __shfl_xor(em, off, 64));
  if (lane == 0) red[wv] = em;

  // ---- stage z -> bf16 into buf0 rows 0..63 (swizzled); ||z|| ----
  #pragma unroll
  for (int pass = 0; pass < 4; ++pass) {
    int row = pass * 16 + (t >> 4);
    const float* zr = z + (size_t)(n0 + row) * 256;
    float ssq = 0.f;
    #pragma unroll
    for (int j = 0; j < 2; ++j) {
      float4 a = *reinterpret_cast<const float4*>(zr + q16 * 16 + j * 8);
      float4 b = *reinterpret_cast<const float4*>(zr + q16 * 16 + j * 8 + 4);
      ssq += a.x*a.x + a.y*a.y + a.z*a.z + a.w*a.w
           + b.x*b.x + b.y*b.y + b.z*b.z + b.w*b.w;
      int g = q16 * 2 + j;                       // logical granule 0..31
      *reinterpret_cast<uint4*>(&sbuf[row * 256 + ((g ^ (row & 7)) * 8)]) = pack8(a, b);
    }
    #pragma unroll
    for (int off = 1; off < 16; off <<= 1) ssq += __shfl_xor(ssq, off, 64);
    if (q16 == 0) znorm[row] = sqrtf(ssq);
  }
  __syncthreads();  // S1: z staged, red[] ready

  const float enmax = sqrtf(fmaxf(fmaxf(red[0], red[1]), fmaxf(red[2], red[3])));

  // ---- token fragments (B operand) into registers: 32 tokens x 256 dims ----
  // B layout for 32x32x16: col = lane&31 (token), k = (lane>>5)*8 + e.
  bf16x8 tfrag[16];
  {
    int row = ts * 32 + l31;
    #pragma unroll
    for (int kk = 0; kk < 16; ++kk) {
      int g = (kk * 2 + hk) ^ (row & 7);
      tfrag[kk] = *reinterpret_cast<const bf16x8*>(&sbuf[row * 256 + g * 8]);
    }
  }
  const float zn = znorm[ts * 32 + l31];
  __syncthreads();  // S2: all token-frag loads done before chunk 0 overwrites buf0

  // ---- prologue: issue chunk 0 -> buf0 (async DMA), wait, publish ----
  {
    #pragma unroll
    for (int i = 0; i < 8; ++i) {
      int f = (wv * 8 + i) * 64 + lane;          // granule 0..2047
      int row = f >> 5, slot = f & 31;
      gload16(cb_bf + (size_t)row * 256 + ((slot ^ (row & 7)) * 8),
              &sbuf[(size_t)(wv * 512 + i * 64) * 8]);
    }
  }
  asm volatile("s_waitcnt vmcnt(0)" ::: "memory");
  __syncthreads();  // S3: chunk 0 visible

  float am = 3.4e38f;                            // register gate (tightens only)
  const int tok = ts * 32 + l31;                 // this lane's token

  // ---- chunk loop: 16 chunks x 64 codes, double-buffered async staging ----
  for (int lc = 0; lc < NCH; ++lc) {
    const int kbase = lc * CH;
    unsigned short* cur = &sbuf[(lc & 1) * BUFW];
    unsigned short* nxt = &sbuf[((lc + 1) & 1) * BUFW];
    if (lc < NCH - 1) {  // issue next chunk's DMA before compute
      const unsigned short* base = cb_bf + (size_t)(kbase + CH) * 256;
      #pragma unroll
      for (int i = 0; i < 8; ++i) {
        int f = (wv * 8 + i) * 64 + lane;
        int row = f >> 5, slot = f & 31;
        gload16(base + (size_t)row * 256 + ((slot ^ (row & 7)) * 8),
                nxt + (size_t)(wv * 512 + i * 64) * 8);
      }
    }

    // A operand (codes): row = cs*32 + l31, k = hk*8 + e per kk-slice.
    f32x16 acc = (f32x16){0.f};
    const int arow = cs * 32 + l31;
    const unsigned short* abase = &cur[arow * 256];
    const int asw = arow & 7;
    __builtin_amdgcn_s_setprio(1);
    #pragma unroll
    for (int kk = 0; kk < 16; ++kk) {
      bf16x8 a = *reinterpret_cast<const bf16x8*>(abase + (((kk * 2 + hk) ^ asw) * 8));
      acc = __builtin_amdgcn_mfma_f32_32x32x16_bf16(a, tfrag[kk], acc, 0, 0, 0);
    }
    __builtin_amdgcn_s_setprio(0);

    // screen: lane holds 16 codes of token `tok`:
    // code(reg) = kbase + cs*32 + (reg&3) + 8*(reg>>2) + 4*hk
    const int cb0 = kbase + cs * 32 + hk * 4;
    float4 ee4[4];
    #pragma unroll
    for (int gg = 0; gg < 4; ++gg)
      ee4[gg] = *reinterpret_cast<const float4*>(&ee_lds[cb0 + 8 * gg]);

    float dm = 3.4e38f;
    #pragma unroll
    for (int gg = 0; gg < 4; ++gg) {
      float d0 = ee4[gg].x - 2.f * acc[gg * 4 + 0];
      float d1 = ee4[gg].y - 2.f * acc[gg * 4 + 1];
      float d2 = ee4[gg].z - 2.f * acc[gg * 4 + 2];
      float d3 = ee4[gg].w - 2.f * acc[gg * 4 + 3];
      dm = fminf(dm, fminf(fminf(d0, d1), fminf(d2, d3)));
    }
    dm = fmaxf(dm, 0.f);
    atomicMin(&umin[tok], __float_as_uint(dm));   // 2-way same-address
    am = fminf(am, __uint_as_float(umin[tok]));   // gate read (in-order after publish)

    if (dm <= am + 1.5f + 0.002f * zn * enmax) {  // guard: lane's best vs loosest bound
      #pragma unroll
      for (int gg = 0; gg < 4; ++gg) {
        #pragma unroll
        for (int jj = 0; jj < 4; ++jj) {
          float eej = (jj == 0) ? ee4[gg].x : (jj == 1) ? ee4[gg].y
                    : (jj == 2) ? ee4[gg].z : ee4[gg].w;
          float d = eej - 2.f * acc[gg * 4 + jj];
          if (d <= am + 1.5f + 0.002f * zn * sqrtf(eej)) {
            int code = cb0 + 8 * gg + jj;
            int sl = atomicAdd(&ccnt[tok], 1);
            if (sl < MAXC) cand[tok * MAXC + sl] =
                (__float_as_uint(fmaxf(d, 0.f)) & 0xFFFFFC00u) | (unsigned)code;
          }
        }
      }
    }
    asm volatile("s_waitcnt vmcnt(0)" ::: "memory");  // next-chunk DMA landed
    __syncthreads();                                  // visible to all waves
  }

  // ---- phase 1: two-tier exact rescore (tokens wave-private: wv*16+it) ----
  for (int it = 0; it < 16; ++it) {
    int tk = wv * 16 + it;
    int n = n0 + tk;
    int cnt = ccnt[tk];
    int bk = 0;
    if (cnt > MAXC) {  // overflow safety net: exact scan of all K, 2-unrolled
      float4 zv = *reinterpret_cast<const float4*>(z + (size_t)n * 256 + lane * 4);
      float bs = 3.4e38f;
      for (int k = 0; k < K; k += 2) {
        float4 ca = *reinterpret_cast<const float4*>(cb + (size_t)k * 256 + lane * 4);
        float4 cbv = *reinterpret_cast<const float4*>(cb + (size_t)(k + 1) * 256 + lane * 4);
        float pa = zv.x * ca.x + zv.y * ca.y + zv.z * ca.z + zv.w * ca.w;
        float pb = zv.x * cbv.x + zv.y * cbv.y + zv.z * cbv.z + zv.w * cbv.w;
        #pragma unroll
        for (int off = 32; off; off >>= 1) {
          pa += __shfl_xor(pa, off, 64);
          pb += __shfl_xor(pb, off, 64);
        }
        float sa = ee_lds[k] - 2.f * pa;
        float sb = ee_lds[k + 1] - 2.f * pb;
        if (sa < bs) { bs = sa; bk = k; }
        if (sb < bs) { bs = sb; bk = k + 1; }
      }
    } else {
      // tier 1: flag candidates within margin of the exact screen-min
      float thr = __uint_as_float(umin[tk]) + 1.5f + 0.002f * znorm[tk] * enmax;
      int c = (lane < cnt) ? lane : 0;
      unsigned pe = cand[tk * MAXC + c];
      bool flag = (lane < cnt) && (__uint_as_float(pe & 0xFFFFFC00u) <= thr);
      unsigned long long msk = __ballot(flag);
      if (__popcll(msk) == 1) {
        int cc = __ffsll((long long)msk) - 1;
        bk = (int)(cand[tk * MAXC + cc] & 1023u);   // unique in-margin == argmin
      } else {
        // tier 2: 4-way-unrolled exact fp32 rescore over all cnt
        float4 zv = *reinterpret_cast<const float4*>(z + (size_t)n * 256 + lane * 4);
        float bs = 3.4e38f; bk = 1 << 29;
        int cc = 0;
        for (; cc + 4 <= cnt; cc += 4) {
          int k0 = cand[tk * MAXC + cc]     & 1023;
          int k1 = cand[tk * MAXC + cc + 1] & 1023;
          int k2 = cand[tk * MAXC + cc + 2] & 1023;
          int k3 = cand[tk * MAXC + cc + 3] & 1023;
          float4 e0 = *reinterpret_cast<const float4*>(cb + (size_t)k0 * 256 + lane * 4);
          float4 e1 = *reinterpret_cast<const float4*>(cb + (size_t)k1 * 256 + lane * 4);
          float4 e2 = *reinterpret_cast<const float4*>(cb + (size_t)k2 * 256 + lane * 4);
          float4 e3 = *reinterpret_cast<const float4*>(cb + (size_t)k3 * 256 + lane * 4);
          float p0 = zv.x * e0.x + zv.y * e0.y + zv.z * e0.z + zv.w * e0.w;
          float p1 = zv.x * e1.x + zv.y * e1.y + zv.z * e1.z + zv.w * e1.w;
          float p2 = zv.x * e2.x + zv.y * e2.y + zv.z * e2.z + zv.w * e2.w;
          float p3 = zv.x * e3.x + zv.y * e3.y + zv.z * e3.z + zv.w * e3.w;
          #pragma unroll
          for (int off = 32; off; off >>= 1) {   // 4 independent reduce chains
            p0 += __shfl_xor(p0, off, 64);
            p1 += __shfl_xor(p1, off, 64);
            p2 += __shfl_xor(p2, off, 64);
            p3 += __shfl_xor(p3, off, 64);
          }
          float s0 = ee_lds[k0] - 2.f * p0;
          float s1 = ee_lds[k1] - 2.f * p1;
          float s2 = ee_lds[k2] - 2.f * p2;
          float s3 = ee_lds[k3] - 2.f * p3;
          if (s0 < bs || (s0 == bs && k0 < bk)) { bs = s0; bk = k0; }
          if (s1 < bs || (s1 == bs && k1 < bk)) { bs = s1; bk = k1; }
          if (s2 < bs || (s2 == bs && k2 < bk)) { bs = s2; bk = k2; }
          if (s3 < bs || (s3 == bs && k3 < bk)) { bs = s3; bk = k3; }
        }
        for (; cc < cnt; ++cc) {
          int k = cand[tk * MAXC + cc] & 1023;
          float4 ev = *reinterpret_cast<const float4*>(cb + (size_t)k * 256 + lane * 4);
          float dp = zv.x * ev.x + zv.y * ev.y + zv.z * ev.z + zv.w * ev.w;
          #pragma unroll
          for (int off = 32; off; off >>= 1) dp += __shfl_xor(dp, off, 64);
          float s = ee_lds[k] - 2.f * dp;   // identical on all lanes
          if (s < bs || (s == bs && k < bk)) { bs = s; bk = k; }
        }
      }
    }
    bkbuf[tk] = (unsigned short)bk;
  }

  // ---- phase 2: outputs + loss, 2 tokens in flight ----
  float lsum = 0.f, msum = 0.f;
  for (int it = 0; it < 16; it += 2) {
    int tokA = wv * 16 + it, tokB = tokA + 1;
    int na = n0 + tokA, nb = n0 + tokB;
    int ba = bkbuf[tokA], bb = bkbuf[tokB];
    float4 za = *reinterpret_cast<const float4*>(z + (size_t)na * 256 + lane * 4);
    float4 zb = *reinterpret_cast<const float4*>(z + (size_t)nb * 256 + lane * 4);
    float4 qa = *reinterpret_cast<const float4*>(cb + (size_t)ba * 256 + lane * 4);
    float4 qb = *reinterpret_cast<const float4*>(cb + (size_t)bb * 256 + lane * 4);
    float ma = mask[na], mb = mask[nb];
    float4 oa; oa.x = qa.x * ma; oa.y = qa.y * ma; oa.z = qa.z * ma; oa.w = qa.w * ma;
    float4 ob; ob.x = qb.x * mb; ob.y = qb.y * mb; ob.z = qb.z * mb; ob.w = qb.w * mb;
    *reinterpret_cast<float4*>(out_q + (size_t)na * 256 + lane * 4) = oa;
    *reinterpret_cast<float4*>(out_q + (size_t)nb * 256 + lane * 4) = ob;
    float dxa = za.x - qa.x, dya = za.y - qa.y, dza = za.z - qa.z, dwa = za.w - qa.w;
    float dxb = zb.x - qb.x, dyb = zb.y - qb.y, dzb = zb.z - qb.z, dwb = zb.w - qb.w;
    lsum = fmaf(ma, dxa * dxa + dya * dya + dza * dza + dwa * dwa, lsum);
    lsum = fmaf(mb, dxb * dxb + dyb * dyb + dzb * dzb + dwb * dwb, lsum);
    if (lane == 0) {
      msum += ma + mb;
      out_idx_f[na] = (ma > 0.f) ? (float)ba : 0.f;
      out_idx_f[nb] = (mb > 0.f) ? (float)bb : 0.f;
    }
  }
  #pragma unroll
  for (int off = 32; off; off >>= 1) lsum += __shfl_down(lsum, off, 64);
  if (lane == 0) { red[wv] = lsum; red[4 + wv] = msum; }
  __syncthreads();
  if (t == 0) {
    atomicAdd(&acc2[0], red[0] + red[1] + red[2] + red[3]);
    atomicAdd(&acc2[1], red[4] + red[5] + red[6] + red[7]);
    __threadfence();
    int prev = atomicAdd(done_ctr, 1);
    last = (prev == nblocks - 1);
  }
  __syncthreads();
  if (last && t == 0) {
    float s  = atomicAdd(&acc2[0], 0.0f);
    float nv = atomicAdd(&acc2[1], 0.0f);
    out_loss[0] = (nv > 0.f) ? (0.25f * s / (nv * 256.0f)) : 0.0f;
  }
}

// ---------------------------------------------------------------------------
extern "C" void kernel_launch(void* const* d_in, const int* in_sizes, int n_in,
                              void* d_out, int out_size, void* d_ws, size_t ws_size,
                              hipStream_t stream) {
  const float* z    = (const float*)d_in[0];  // (N, 256)
  const float* mask = (const float*)d_in[1];  // (N,)
  const float* cb   = (const float*)d_in[2];  // (K, 256)
  const int N = in_sizes[1];                  // 32768
  const int D = 256;
  const int K = in_sizes[2] / D;              // 1024

  float* wsf  = (float*)d_ws;
  float* acc2 = wsf;                          // 2 floats
  int*   dctr = (int*)(wsf + 2);              // 1 int
  float* ee   = wsf + 8;                      // K floats
  unsigned short* cb_bf = (unsigned short*)(ee + K);  // K*256 bf16

  float* out_q     = (float*)d_out;           // N*D
  float* out_loss  = out_q + (size_t)N * D;   // 1
  float* out_idx_f = out_loss + 1;            // N

  vq_prep<<<(K + 3) / 4, 256, 0, stream>>>(cb, cb_bf, ee, acc2, dctr, K);
  vq_main<<<N / TOK, 256, 0, stream>>>(z, cb, cb_bf, ee, mask, out_q,
                                       out_idx_f, out_loss, acc2, dctr, N / TOK, K);
}